// Round 4
// baseline (948.590 us; speedup 1.0000x reference)
//
#include <hip/hip_runtime.h>
#include <hip/hip_fp16.h>

typedef unsigned short u16;
typedef float f32x4 __attribute__((ext_vector_type(4)));
typedef _Float16 half8 __attribute__((ext_vector_type(8)));
typedef unsigned short u16x4 __attribute__((ext_vector_type(4)));

#define CDIM 768
#define NP 1024
#define NB 32

static constexpr size_t CHW = (size_t)NB * CDIM * NP;  // 25,165,824

// workspace layout (bytes)
static constexpr size_t XT_OFF  = 0;                         // f16 [b][p][c]; later reused as aoT f16
static constexpr size_t HS_OFF  = CHW * 2;                   // fp32 hs11, hs111 (2*CHW*4)
static constexpr size_t WHI_OFF = HS_OFF + CHW * 8;          // f16 hi
static constexpr size_t WLO_OFF = WHI_OFF + (size_t)9 * CDIM * CDIM * 2;

__device__ __forceinline__ u16 f16bits(float f) {
  return __half_as_ushort(__float2half_rn(f));
}

typedef __attribute__((address_space(1))) void gv_t;
typedef __attribute__((address_space(3))) void lv_t;
__device__ __forceinline__ void gload_lds16(const void* g, void* l) {
  __builtin_amdgcn_global_load_lds((gv_t*)g, (lv_t*)l, 16, 0, 0);
}

// ---------------- split W (fp32 -> f16 hi + f16 lo) ----------------
__global__ __launch_bounds__(256) void split_w_k(const float* __restrict__ W,
                                                 u16* __restrict__ hi, u16* __restrict__ lo) {
  int i = blockIdx.x * 256 + threadIdx.x;
  float4 v = ((const float4*)W)[i];
  float f[4] = {v.x, v.y, v.z, v.w};
  u16 hh[4], ll[4];
#pragma unroll
  for (int e = 0; e < 4; ++e) {
    __half h = __float2half_rn(f[e]);
    hh[e] = __half_as_ushort(h);
    ll[e] = f16bits(f[e] - __half2float(h));
  }
  u16x4 h4 = {hh[0], hh[1], hh[2], hh[3]};
  u16x4 l4v = {ll[0], ll[1], ll[2], ll[3]};
  ((u16x4*)hi)[i] = h4;
  ((u16x4*)lo)[i] = l4v;
}

// ---------------- transpose + f16 cast: src fp32 [b][c][p] -> dst f16 [b][p][c] ----------------
__global__ __launch_bounds__(256) void transpose_f16_k(const float* __restrict__ src,
                                                       u16* __restrict__ dxt) {
  __shared__ float tle[32][33];
  const int b = blockIdx.z, c0 = blockIdx.y * 32, p0 = blockIdx.x * 32;
  const int tid = threadIdx.x;
  const int lr = tid >> 5, lc = tid & 31;
  const float* s = src + ((size_t)b * CDIM + c0) * NP + p0;
#pragma unroll
  for (int it = 0; it < 4; ++it) {
    int c = it * 8 + lr;
    tle[c][lc] = s[(size_t)c * NP + lc];
  }
  __syncthreads();
#pragma unroll
  for (int it = 0; it < 4; ++it) {
    int p = it * 8 + lr;
    float v = tle[lc][p];
    size_t off = ((size_t)b * NP + p0 + p) * CDIM + c0 + lc;
    dxt[off] = f16bits(v);
  }
}

// ---------------- spatial permutations ----------------
__device__ __forceinline__ int sigma_fn(int mode, int z, int t, int p) {
  if (t == 0 || mode == 1) return p;
  int i = p >> 5, j = p & 31;
  if (z == 0) {
    if (t == 1) return (j << 5) | (31 - i);
    if (t == 2) return ((31 - i) << 5) | (31 - j);
    return ((31 - j) << 5) | i;
  } else {
    int ib = i & 16, jb = j & 16, il = i & 15, jl = j & 15;
    if (t == 1) return ((ib | jl) << 5) | (jb | (15 - il));
    if (t == 2) return ((ib | (15 - il)) << 5) | (jb | (15 - jl));
    return ((ib | (15 - jl)) << 5) | (jb | il);
  }
}

// ---------------- pipelined multi-term 2x-f16-split GEMM, m201-style fine phases ----------------
// Tile 128(o) x 256(p), BK=32, 512 threads (8 waves, 2Mx4N, wave tile 64x64),
// 3 LDS buffers x 32KB, counted vmcnt(4), depth-2 prefetch,
// 2 phases/step: {ds_read subtile; 2 gload_lds; barrier; lgkm0; setprio1; 16 MFMA; setprio0; barrier}
__global__ __launch_bounds__(512, 2) void gemm_p(
    const u16* __restrict__ Whi, const u16* __restrict__ Wlo,
    const u16* __restrict__ Bx,
    const float* __restrict__ bias, float* __restrict__ dst,
    int nterms, int wselBase, int mode) {
  extern __shared__ u16 lds[];  // 3 x 16384 u16; per buf: A [0,8192), B [8192,16384)
  const int tid = threadIdx.x;
  const int lane = tid & 63;
  const int w = tid >> 6;
  const int wr = w >> 2, wc = w & 3;
  const int z = blockIdx.z;
  const int b = blockIdx.x >> 2;
  const int p0 = (blockIdx.x & 3) << 8;
  const int o0 = blockIdx.y << 7;
  const int l15 = lane & 15, l4 = lane >> 4;

  float* dstz = dst + (size_t)z * CHW;
  const int NSTEP = nterms * 24;

  // A staging: slots d in [0,1024): row=d>>3 (0..127), chunk c3=(d&7)^(row&7);
  //   c3 bit2 -> hi/lo matrix, bits0-1 -> k-subchunk of 8 u16.
  auto stageA = [&](int s, int buf) {
    int term = (s * 2731) >> 16;
    int k0 = (s - term * 24) * 32;
    int wsel = wselBase + z * 4 + term;
    u16* lb = &lds[(size_t)buf * 16384];
#pragma unroll
    for (int it = 0; it < 2; ++it) {
      int d = it * 512 + tid;
      int row = d >> 3, c3 = (d & 7) ^ (row & 7);
      const u16* src = ((c3 & 4) ? Wlo : Whi) +
                       ((size_t)wsel * CDIM + o0 + row) * CDIM + (c3 & 3) * 8 + k0;
      gload_lds16(src, lb + (size_t)d * 8);
    }
  };
  // B staging: slots d in [0,1024): row=d>>2 (0..255), stored chunk d&3,
  //   logical k8 = (d&3)^((row>>1)&3).
  auto stageB = [&](int s, int buf) {
    int term = (s * 2731) >> 16;
    int k0 = (s - term * 24) * 32;
    u16* lb = &lds[(size_t)buf * 16384 + 8192];
#pragma unroll
    for (int it = 0; it < 2; ++it) {
      int d = it * 512 + tid;
      int row = d >> 2, k8 = (d & 3) ^ ((row >> 1) & 3);
      int srow = sigma_fn(mode, z, term, p0 + row);
      const u16* src = Bx + ((size_t)b * NP + srow) * CDIM + k8 * 8 + k0;
      gload_lds16(src, lb + (size_t)d * 8);
    }
  };

  f32x4 acc[4][4], racc[4][4];
#pragma unroll
  for (int m = 0; m < 4; ++m)
#pragma unroll
    for (int n = 0; n < 4; ++n) {
      acc[m][n] = (f32x4){0.f, 0.f, 0.f, 0.f};
      racc[m][n] = (f32x4){0.f, 0.f, 0.f, 0.f};
    }
  float4 bvm[4];

  stageA(0, 0); stageB(0, 0);
  stageA(1, 1); stageB(1, 1);
  asm volatile("s_waitcnt vmcnt(4)" ::: "memory");   // buf0 landed; buf1 in flight
  __builtin_amdgcn_s_barrier();
  asm volatile("" ::: "memory");

  int cur = 0;
  for (int s = 0; s < NSTEP; ++s) {
    const int term = (s * 2731) >> 16;
    const int kk = s - term * 24;
    const u16* la = &lds[(size_t)cur * 16384];
    const u16* lbs = la + 8192;
    int nb = cur + 2; if (nb >= 3) nb -= 3;

    // bias preload early so it sits between stage(s+1) and stage(s+2) in the vmcnt FIFO
    if (kk == 0) {
      int wsel = wselBase + z * 4 + term;
#pragma unroll
      for (int m = 0; m < 4; ++m)
        bvm[m] = *(const float4*)&bias[wsel * CDIM + o0 + wr * 64 + m * 16 + l4 * 4];
    }

    // ======== phase 0: A-frags m0,m1 + all B-frags; stage A(s+2); MFMA m0,m1 ========
    half8 a0h, a0l, a1h, a1l, b0, b1, b2, b3;
    {
      int r0 = wr * 64 + l15;
      a0h = *(const half8*)&la[(r0 * 8 + (l4 ^ (r0 & 7))) * 8];
      a0l = *(const half8*)&la[(r0 * 8 + ((4 + l4) ^ (r0 & 7))) * 8];
      int r1 = r0 + 16;
      a1h = *(const half8*)&la[(r1 * 8 + (l4 ^ (r1 & 7))) * 8];
      a1l = *(const half8*)&la[(r1 * 8 + ((4 + l4) ^ (r1 & 7))) * 8];
      int c0r = wc * 64 + l15;
      b0 = *(const half8*)&lbs[(c0r * 4 + (l4 ^ ((c0r >> 1) & 3))) * 8];
      int c1r = c0r + 16;
      b1 = *(const half8*)&lbs[(c1r * 4 + (l4 ^ ((c1r >> 1) & 3))) * 8];
      int c2r = c0r + 32;
      b2 = *(const half8*)&lbs[(c2r * 4 + (l4 ^ ((c2r >> 1) & 3))) * 8];
      int c3r = c0r + 48;
      b3 = *(const half8*)&lbs[(c3r * 4 + (l4 ^ ((c3r >> 1) & 3))) * 8];
    }
    if (s + 2 < NSTEP) stageA(s + 2, nb);
    __builtin_amdgcn_s_barrier();
    asm volatile("s_waitcnt lgkmcnt(0)" ::: "memory");
    __builtin_amdgcn_s_setprio(1);
#pragma unroll
    for (int n = 0; n < 4; ++n) {
      half8 bn = (n == 0) ? b0 : (n == 1) ? b1 : (n == 2) ? b2 : b3;
      acc[0][n] = __builtin_amdgcn_mfma_f32_16x16x32_f16(a0h, bn, acc[0][n], 0, 0, 0);
      acc[0][n] = __builtin_amdgcn_mfma_f32_16x16x32_f16(a0l, bn, acc[0][n], 0, 0, 0);
      acc[1][n] = __builtin_amdgcn_mfma_f32_16x16x32_f16(a1h, bn, acc[1][n], 0, 0, 0);
      acc[1][n] = __builtin_amdgcn_mfma_f32_16x16x32_f16(a1l, bn, acc[1][n], 0, 0, 0);
    }
    __builtin_amdgcn_s_setprio(0);
    __builtin_amdgcn_s_barrier();

    // ======== phase 1: A-frags m2,m3; stage B(s+2); MFMA m2,m3 ========
    half8 a2h, a2l, a3h, a3l;
    {
      int r2 = wr * 64 + 32 + l15;
      a2h = *(const half8*)&la[(r2 * 8 + (l4 ^ (r2 & 7))) * 8];
      a2l = *(const half8*)&la[(r2 * 8 + ((4 + l4) ^ (r2 & 7))) * 8];
      int r3v = r2 + 16;
      a3h = *(const half8*)&la[(r3v * 8 + (l4 ^ (r3v & 7))) * 8];
      a3l = *(const half8*)&la[(r3v * 8 + ((4 + l4) ^ (r3v & 7))) * 8];
    }
    if (s + 2 < NSTEP) stageB(s + 2, nb);
    __builtin_amdgcn_s_barrier();
    asm volatile("s_waitcnt lgkmcnt(0)" ::: "memory");
    __builtin_amdgcn_s_setprio(1);
#pragma unroll
    for (int n = 0; n < 4; ++n) {
      half8 bn = (n == 0) ? b0 : (n == 1) ? b1 : (n == 2) ? b2 : b3;
      acc[2][n] = __builtin_amdgcn_mfma_f32_16x16x32_f16(a2h, bn, acc[2][n], 0, 0, 0);
      acc[2][n] = __builtin_amdgcn_mfma_f32_16x16x32_f16(a2l, bn, acc[2][n], 0, 0, 0);
      acc[3][n] = __builtin_amdgcn_mfma_f32_16x16x32_f16(a3h, bn, acc[3][n], 0, 0, 0);
      acc[3][n] = __builtin_amdgcn_mfma_f32_16x16x32_f16(a3l, bn, acc[3][n], 0, 0, 0);
    }
    __builtin_amdgcn_s_setprio(0);

    if (kk == 23) {  // term boundary: relu(acc + bias) -> racc, reset acc
#pragma unroll
      for (int m = 0; m < 4; ++m) {
        float bvf[4] = {bvm[m].x, bvm[m].y, bvm[m].z, bvm[m].w};
#pragma unroll
        for (int n = 0; n < 4; ++n)
#pragma unroll
          for (int r = 0; r < 4; ++r) {
            racc[m][n][r] += fmaxf(0.f, acc[m][n][r] + bvf[r]);
            acc[m][n][r] = 0.f;
          }
      }
    }

    // step-end: ensure next buffer landed chip-wide; keep stage(s+2) in flight
    if (s + 2 < NSTEP) {
      asm volatile("s_waitcnt vmcnt(4)" ::: "memory");
      __builtin_amdgcn_s_barrier();
      asm volatile("" ::: "memory");
    } else if (s + 1 < NSTEP) {
      asm volatile("s_waitcnt vmcnt(0)" ::: "memory");
      __builtin_amdgcn_s_barrier();
      asm volatile("" ::: "memory");
    }
    cur = cur == 2 ? 0 : cur + 1;
  }

  // C write: row = o0+wr*64+m*16+l4*4+r, col = p0+wc*64+n*16+l15
#pragma unroll
  for (int m = 0; m < 4; ++m) {
    int rowb = o0 + wr * 64 + m * 16 + l4 * 4;
#pragma unroll
    for (int n = 0; n < 4; ++n) {
      int col = p0 + wc * 64 + n * 16 + l15;
      float* dp = dstz + ((size_t)b * CDIM + rowb) * NP + col;
#pragma unroll
      for (int r = 0; r < 4; ++r) dp[(size_t)r * NP] = racc[m][n][r];
    }
  }
}

// ---------------- per-(b,c) 32x32 attention, fp32, fused transposed-f16 output ----------------
__global__ __launch_bounds__(256) void attn_f_k(const float* __restrict__ hs, u16* __restrict__ aoT) {
  __shared__ float q[4][1056];   // pitch 33
  __shared__ float kk[4][1056];
  const int tid = threadIdx.x, w = tid >> 6, lane = tid & 63;
  const int pair0 = blockIdx.x * 4;
  const int b = pair0 / CDIM;
  const int c0 = pair0 % CDIM;
#pragma unroll
  for (int it = 0; it < 8; ++it) {
    int d4 = it * 256 + tid;
    int pr = d4 >> 9;
    int mat = (d4 >> 8) & 1;
    int off4 = d4 & 255;
    float4 v = *(const float4*)&hs[(size_t)mat * CHW + (size_t)(pair0 + pr) * NP + off4 * 4];
    float* dl = mat ? kk[pr] : q[pr];
    int off = off4 * 4;
    int base = (off >> 5) * 33 + (off & 31);
    dl[base] = v.x; dl[base + 1] = v.y; dl[base + 2] = v.z; dl[base + 3] = v.w;
  }
  __syncthreads();
  const int i = lane & 31, half = lane >> 5, jb = half * 16;
  const float* Q = q[w];
  const float* K = kk[w];
  float qr[32];
#pragma unroll
  for (int tt = 0; tt < 32; ++tt) qr[tt] = Q[i * 33 + tt];
  float a[16];
#pragma unroll
  for (int j = 0; j < 16; ++j) {
    float s = 0.f;
#pragma unroll
    for (int tt = 0; tt < 32; ++tt) s = fmaf(qr[tt], K[tt * 33 + jb + j], s);
    a[j] = s;
  }
  float mx = a[0];
#pragma unroll
  for (int j = 1; j < 16; ++j) mx = fmaxf(mx, a[j]);
  mx = fmaxf(mx, __shfl_xor(mx, 32));
  float ssum = 0.f;
#pragma unroll
  for (int j = 0; j < 16; ++j) { a[j] = expf(a[j] - mx); ssum += a[j]; }
  ssum += __shfl_xor(ssum, 32);
  float inv = 1.f / ssum;
#pragma unroll
  for (int j = 0; j < 16; ++j) a[j] *= inv;
#pragma unroll
  for (int h = 0; h < 32; ++h) {
    float o = 0.f;
#pragma unroll
    for (int j = 0; j < 16; ++j) o = fmaf(a[j], Q[(jb + j) * 33 + h], o);
    o += __shfl_xor(o, 32);
    if (half == (h >> 4)) kk[w][i * 33 + h] = o;
  }
  __syncthreads();
#pragma unroll
  for (int it = 0; it < 4; ++it) {
    int p = it * 256 + tid;
    int base = (p >> 5) * 33 + (p & 31);
    ushort4 v;
    v.x = f16bits(kk[0][base]);
    v.y = f16bits(kk[1][base]);
    v.z = f16bits(kk[2][base]);
    v.w = f16bits(kk[3][base]);
    *(ushort4*)&aoT[((size_t)b * NP + p) * CDIM + c0] = v;
  }
}

extern "C" void kernel_launch(void* const* d_in, const int* in_sizes, int n_in,
                              void* d_out, int out_size, void* d_ws, size_t ws_size,
                              hipStream_t stream) {
  (void)in_sizes; (void)n_in; (void)out_size; (void)ws_size;
  const float* x = (const float*)d_in[0];
  const float* Ws = (const float*)d_in[1];
  const float* bs = (const float*)d_in[2];
  float* out = (float*)d_out;
  char* ws = (char*)d_ws;

  u16* XT  = (u16*)(ws + XT_OFF);
  float* hs = (float*)(ws + HS_OFF);
  u16* Whi = (u16*)(ws + WHI_OFF);
  u16* Wlo = (u16*)(ws + WLO_OFF);
  u16* aoT = (u16*)(ws + XT_OFF);   // aliases XT (dead after stage-1)

  split_w_k<<<5184, 256, 0, stream>>>(Ws, Whi, Wlo);
  transpose_f16_k<<<dim3(32, 24, 32), 256, 0, stream>>>(x, XT);
  // stage-1: hs11 (z=0, W0..3) and hs111 (z=1, W4..7); 128x256 tiles
  gemm_p<<<dim3(128, 6, 2), 512, 98304, stream>>>(Whi, Wlo, XT, bs, hs, 4, 0, 0);
  attn_f_k<<<6144, 256, 0, stream>>>(hs, aoT);
  // final conv: relu(W8 @ attout + b8) -> d_out
  gemm_p<<<dim3(128, 6, 1), 512, 98304, stream>>>(Whi, Wlo, aoT, bs, out, 1, 8, 1);
}

// Round 5
// 825.007 us; speedup vs baseline: 1.1498x; 1.1498x over previous
//
#include <hip/hip_runtime.h>
#include <hip/hip_fp16.h>

typedef unsigned short u16;
typedef float f32x4 __attribute__((ext_vector_type(4)));
typedef _Float16 half8 __attribute__((ext_vector_type(8)));
typedef unsigned short u16x4 __attribute__((ext_vector_type(4)));

#define CDIM 768
#define NP 1024
#define NB 32

static constexpr size_t CHW = (size_t)NB * CDIM * NP;  // 25,165,824

// workspace layout (bytes)
static constexpr size_t XT_OFF  = 0;                         // f16 [b][p][c]; later reused as aoT f16
static constexpr size_t HS_OFF  = CHW * 2;                   // fp32 hs11, hs111 (2*CHW*4)
static constexpr size_t WHI_OFF = HS_OFF + CHW * 8;          // f16 hi
static constexpr size_t WLO_OFF = WHI_OFF + (size_t)9 * CDIM * CDIM * 2;

__device__ __forceinline__ u16 f16bits(float f) {
  return __half_as_ushort(__float2half_rn(f));
}

typedef __attribute__((address_space(1))) void gv_t;
typedef __attribute__((address_space(3))) void lv_t;
__device__ __forceinline__ void gload_lds16(const void* g, void* l) {
  __builtin_amdgcn_global_load_lds((gv_t*)g, (lv_t*)l, 16, 0, 0);
}

// ---------------- split W (fp32 -> f16 hi + f16 lo) ----------------
__global__ __launch_bounds__(256) void split_w_k(const float* __restrict__ W,
                                                 u16* __restrict__ hi, u16* __restrict__ lo) {
  int i = blockIdx.x * 256 + threadIdx.x;
  float4 v = ((const float4*)W)[i];
  float f[4] = {v.x, v.y, v.z, v.w};
  u16 hh[4], ll[4];
#pragma unroll
  for (int e = 0; e < 4; ++e) {
    __half h = __float2half_rn(f[e]);
    hh[e] = __half_as_ushort(h);
    ll[e] = f16bits(f[e] - __half2float(h));
  }
  u16x4 h4 = {hh[0], hh[1], hh[2], hh[3]};
  u16x4 l4v = {ll[0], ll[1], ll[2], ll[3]};
  ((u16x4*)hi)[i] = h4;
  ((u16x4*)lo)[i] = l4v;
}

// ---------------- transpose + f16 cast: src fp32 [b][c][p] -> dst f16 [b][p][c] ----------------
__global__ __launch_bounds__(256) void transpose_f16_k(const float* __restrict__ src,
                                                       u16* __restrict__ dxt) {
  __shared__ float tle[32][33];
  const int b = blockIdx.z, c0 = blockIdx.y * 32, p0 = blockIdx.x * 32;
  const int tid = threadIdx.x;
  const int lr = tid >> 5, lc = tid & 31;
  const float* s = src + ((size_t)b * CDIM + c0) * NP + p0;
#pragma unroll
  for (int it = 0; it < 4; ++it) {
    int c = it * 8 + lr;
    tle[c][lc] = s[(size_t)c * NP + lc];
  }
  __syncthreads();
#pragma unroll
  for (int it = 0; it < 4; ++it) {
    int p = it * 8 + lr;
    float v = tle[lc][p];
    size_t off = ((size_t)b * NP + p0 + p) * CDIM + c0 + lc;
    dxt[off] = f16bits(v);
  }
}

// ---------------- spatial permutations ----------------
__device__ __forceinline__ int sigma_fn(int mode, int z, int t, int p) {
  if (t == 0 || mode == 1) return p;
  int i = p >> 5, j = p & 31;
  if (z == 0) {
    if (t == 1) return (j << 5) | (31 - i);
    if (t == 2) return ((31 - i) << 5) | (31 - j);
    return ((31 - j) << 5) | i;
  } else {
    int ib = i & 16, jb = j & 16, il = i & 15, jl = j & 15;
    if (t == 1) return ((ib | jl) << 5) | (jb | (15 - il));
    if (t == 2) return ((ib | (15 - il)) << 5) | (jb | (15 - jl));
    return ((ib | (15 - jl)) << 5) | (jb | il);
  }
}

// ---------------- pipelined multi-term 2x-f16-split GEMM, BK=64, precomputed offsets ----------------
// Tile 128(o) x 256(p), 512 threads (8 waves, 2Mx4N, wave tile 64x64), BK=64 channels.
// 2 LDS buffers x 64KB (A 32KB: [128 rows][16 chunks of 8 u16], chunk = logical^(row&7) low3,
// bit3 = hi/lo; B 32KB: [256 rows][8 chunks], chunk = logical^(row&7)).
// Depth-1 prefetch, vmcnt(0)+1 barrier per step, steady-state VALU = pointer increments only.
__global__ __launch_bounds__(512, 2) void gemm_p(
    const u16* __restrict__ Whi, const u16* __restrict__ Wlo,
    const u16* __restrict__ Bx,
    const float* __restrict__ bias, float* __restrict__ dst,
    int nterms, int wselBase, int mode) {
  extern __shared__ u16 lds[];  // 2 x 32768 u16
  const int tid = threadIdx.x;
  const int lane = tid & 63;
  const int w = tid >> 6;
  const int wr = w >> 2, wc = w & 3;
  const int z = blockIdx.z;
  const int b = blockIdx.x >> 2;
  const int p0 = (blockIdx.x & 3) << 8;
  const int o0 = blockIdx.y << 7;
  const int l15 = lane & 15, l4 = lane >> 4;
  const int s7 = l15 & 7;

  float* dstz = dst + (size_t)z * CHW;
  const int NSTEP = nterms * 12;

  // LDS read base offsets (u16 units). A frag (m,h,kh): idx = baseA[kh] + m*2048 + h*64.
  // B frag (n,kh): idx = baseB[kh] + n*1024.
  const int baseA0 = (wr * 64 + l15) * 128 + ((l4) ^ s7) * 8;
  const int baseA1 = (wr * 64 + l15) * 128 + ((4 + l4) ^ s7) * 8;
  const int baseB0 = 16384 + (wc * 64 + l15) * 64 + ((l4) ^ s7) * 8;
  const int baseB1 = 16384 + (wc * 64 + l15) * 64 + ((4 + l4) ^ s7) * 8;

  // staging decode (per-thread constants)
  int arow[4], acof[4], ahsel[4], adst[4];
  int brow[4], bcof[4], bdst[4];
#pragma unroll
  for (int it = 0; it < 4; ++it) {
    int d = it * 512 + tid;
    arow[it] = d >> 4;
    int c = d & 15;
    ahsel[it] = c >> 3;
    acof[it] = ((c & 7) ^ (arow[it] & 7)) * 8;
    adst[it] = d * 8;
    brow[it] = d >> 3;
    bcof[it] = ((d & 7) ^ (brow[it] & 7)) * 8;
    bdst[it] = 16384 + d * 8;
  }

  const u16* aptr[4];
  const u16* bptr[4];
  auto setPtrs = [&](int term) {
    int wsel = wselBase + z * 4 + term;
#pragma unroll
    for (int it = 0; it < 4; ++it) {
      aptr[it] = (ahsel[it] ? Wlo : Whi) +
                 ((size_t)wsel * CDIM + o0 + arow[it]) * CDIM + acof[it];
      int srow = sigma_fn(mode, z, term, p0 + brow[it]);
      bptr[it] = Bx + ((size_t)b * NP + srow) * CDIM + bcof[it];
    }
  };

  f32x4 acc[4][4], racc[4][4];
#pragma unroll
  for (int m = 0; m < 4; ++m)
#pragma unroll
    for (int n = 0; n < 4; ++n) {
      acc[m][n] = (f32x4){0.f, 0.f, 0.f, 0.f};
      racc[m][n] = (f32x4){0.f, 0.f, 0.f, 0.f};
    }
  float4 bvm[4];

  // prologue: stage step 0 into buf 0
  setPtrs(0);
#pragma unroll
  for (int it = 0; it < 4; ++it) gload_lds16(aptr[it], lds + adst[it]);
#pragma unroll
  for (int it = 0; it < 4; ++it) gload_lds16(bptr[it], lds + bdst[it]);
#pragma unroll
  for (int it = 0; it < 4; ++it) { aptr[it] += 64; bptr[it] += 64; }

  int nsk = 1, nst = 0;        // k-step / term of NEXT stage target
  int ckk = 0, cterm = 0;      // k-step / term being CONSUMED
  int cur = 0;

  for (int s = 0; s < NSTEP; ++s) {
    asm volatile("s_waitcnt vmcnt(0)" ::: "memory");
    __builtin_amdgcn_s_barrier();
    asm volatile("" ::: "memory");

    const u16* la = lds + (cur << 15);
    u16* ldst = lds + ((cur ^ 1) << 15);
    const bool dostage = (s + 1) < NSTEP;

    if (ckk == 0) {
      int wsel = wselBase + z * 4 + cterm;
#pragma unroll
      for (int m = 0; m < 4; ++m)
        bvm[m] = *(const float4*)&bias[wsel * CDIM + o0 + wr * 64 + m * 16 + l4 * 4];
    }
    if (dostage && nsk == 12) { ++nst; nsk = 0; setPtrs(nst); }

    half8 ah[4], al[4], bb[4];
    // ======== phase 0 (k-half 0): ds_read; stage A(s+1); 32 MFMA ========
#pragma unroll
    for (int m = 0; m < 4; ++m) {
      ah[m] = *(const half8*)(la + baseA0 + m * 2048);
      al[m] = *(const half8*)(la + baseA0 + m * 2048 + 64);
    }
#pragma unroll
    for (int n = 0; n < 4; ++n) bb[n] = *(const half8*)(la + baseB0 + n * 1024);
    if (dostage) {
#pragma unroll
      for (int it = 0; it < 4; ++it) gload_lds16(aptr[it], ldst + adst[it]);
    }
    asm volatile("s_waitcnt lgkmcnt(0)" ::: "memory");
    __builtin_amdgcn_s_setprio(1);
#pragma unroll
    for (int m = 0; m < 4; ++m)
#pragma unroll
      for (int n = 0; n < 4; ++n) {
        acc[m][n] = __builtin_amdgcn_mfma_f32_16x16x32_f16(ah[m], bb[n], acc[m][n], 0, 0, 0);
        acc[m][n] = __builtin_amdgcn_mfma_f32_16x16x32_f16(al[m], bb[n], acc[m][n], 0, 0, 0);
      }
    __builtin_amdgcn_s_setprio(0);

    // ======== phase 1 (k-half 1): ds_read; stage B(s+1); 32 MFMA ========
#pragma unroll
    for (int m = 0; m < 4; ++m) {
      ah[m] = *(const half8*)(la + baseA1 + m * 2048);
      al[m] = *(const half8*)(la + baseA1 + m * 2048 + 64);
    }
#pragma unroll
    for (int n = 0; n < 4; ++n) bb[n] = *(const half8*)(la + baseB1 + n * 1024);
    if (dostage) {
#pragma unroll
      for (int it = 0; it < 4; ++it) gload_lds16(bptr[it], ldst + bdst[it]);
#pragma unroll
      for (int it = 0; it < 4; ++it) { aptr[it] += 64; bptr[it] += 64; }
      ++nsk;
    }
    asm volatile("s_waitcnt lgkmcnt(0)" ::: "memory");
    __builtin_amdgcn_s_setprio(1);
#pragma unroll
    for (int m = 0; m < 4; ++m)
#pragma unroll
      for (int n = 0; n < 4; ++n) {
        acc[m][n] = __builtin_amdgcn_mfma_f32_16x16x32_f16(ah[m], bb[n], acc[m][n], 0, 0, 0);
        acc[m][n] = __builtin_amdgcn_mfma_f32_16x16x32_f16(al[m], bb[n], acc[m][n], 0, 0, 0);
      }
    __builtin_amdgcn_s_setprio(0);

    if (ckk == 11) {  // term boundary: relu(acc + bias) -> racc, reset acc
#pragma unroll
      for (int m = 0; m < 4; ++m) {
        float bvf[4] = {bvm[m].x, bvm[m].y, bvm[m].z, bvm[m].w};
#pragma unroll
        for (int n = 0; n < 4; ++n)
#pragma unroll
          for (int r = 0; r < 4; ++r) {
            racc[m][n][r] += fmaxf(0.f, acc[m][n][r] + bvf[r]);
            acc[m][n][r] = 0.f;
          }
      }
    }
    cur ^= 1;
    ++ckk; if (ckk == 12) { ckk = 0; ++cterm; }
  }

  // C write: row = o0+wr*64+m*16+l4*4+r, col = p0+wc*64+n*16+l15
#pragma unroll
  for (int m = 0; m < 4; ++m) {
    int rowb = o0 + wr * 64 + m * 16 + l4 * 4;
#pragma unroll
    for (int n = 0; n < 4; ++n) {
      int col = p0 + wc * 64 + n * 16 + l15;
      float* dp = dstz + ((size_t)b * CDIM + rowb) * NP + col;
#pragma unroll
      for (int r = 0; r < 4; ++r) dp[(size_t)r * NP] = racc[m][n][r];
    }
  }
}

// ---------------- per-(b,c) 32x32 attention, fp32, fused transposed-f16 output ----------------
__global__ __launch_bounds__(256) void attn_f_k(const float* __restrict__ hs, u16* __restrict__ aoT) {
  __shared__ float q[4][1056];   // pitch 33
  __shared__ float kk[4][1056];
  const int tid = threadIdx.x, w = tid >> 6, lane = tid & 63;
  const int pair0 = blockIdx.x * 4;
  const int b = pair0 / CDIM;
  const int c0 = pair0 % CDIM;
#pragma unroll
  for (int it = 0; it < 8; ++it) {
    int d4 = it * 256 + tid;
    int pr = d4 >> 9;
    int mat = (d4 >> 8) & 1;
    int off4 = d4 & 255;
    float4 v = *(const float4*)&hs[(size_t)mat * CHW + (size_t)(pair0 + pr) * NP + off4 * 4];
    float* dl = mat ? kk[pr] : q[pr];
    int off = off4 * 4;
    int base = (off >> 5) * 33 + (off & 31);
    dl[base] = v.x; dl[base + 1] = v.y; dl[base + 2] = v.z; dl[base + 3] = v.w;
  }
  __syncthreads();
  const int i = lane & 31, half = lane >> 5, jb = half * 16;
  const float* Q = q[w];
  const float* K = kk[w];
  float qr[32];
#pragma unroll
  for (int tt = 0; tt < 32; ++tt) qr[tt] = Q[i * 33 + tt];
  float a[16];
#pragma unroll
  for (int j = 0; j < 16; ++j) {
    float s = 0.f;
#pragma unroll
    for (int tt = 0; tt < 32; ++tt) s = fmaf(qr[tt], K[tt * 33 + jb + j], s);
    a[j] = s;
  }
  float mx = a[0];
#pragma unroll
  for (int j = 1; j < 16; ++j) mx = fmaxf(mx, a[j]);
  mx = fmaxf(mx, __shfl_xor(mx, 32));
  float ssum = 0.f;
#pragma unroll
  for (int j = 0; j < 16; ++j) { a[j] = expf(a[j] - mx); ssum += a[j]; }
  ssum += __shfl_xor(ssum, 32);
  float inv = 1.f / ssum;
#pragma unroll
  for (int j = 0; j < 16; ++j) a[j] *= inv;
#pragma unroll
  for (int h = 0; h < 32; ++h) {
    float o = 0.f;
#pragma unroll
    for (int j = 0; j < 16; ++j) o = fmaf(a[j], Q[(jb + j) * 33 + h], o);
    o += __shfl_xor(o, 32);
    if (half == (h >> 4)) kk[w][i * 33 + h] = o;
  }
  __syncthreads();
#pragma unroll
  for (int it = 0; it < 4; ++it) {
    int p = it * 256 + tid;
    int base = (p >> 5) * 33 + (p & 31);
    ushort4 v;
    v.x = f16bits(kk[0][base]);
    v.y = f16bits(kk[1][base]);
    v.z = f16bits(kk[2][base]);
    v.w = f16bits(kk[3][base]);
    *(ushort4*)&aoT[((size_t)b * NP + p) * CDIM + c0] = v;
  }
}

extern "C" void kernel_launch(void* const* d_in, const int* in_sizes, int n_in,
                              void* d_out, int out_size, void* d_ws, size_t ws_size,
                              hipStream_t stream) {
  (void)in_sizes; (void)n_in; (void)out_size; (void)ws_size;
  const float* x = (const float*)d_in[0];
  const float* Ws = (const float*)d_in[1];
  const float* bs = (const float*)d_in[2];
  float* out = (float*)d_out;
  char* ws = (char*)d_ws;

  u16* XT  = (u16*)(ws + XT_OFF);
  float* hs = (float*)(ws + HS_OFF);
  u16* Whi = (u16*)(ws + WHI_OFF);
  u16* Wlo = (u16*)(ws + WLO_OFF);
  u16* aoT = (u16*)(ws + XT_OFF);   // aliases XT (dead after stage-1)

  split_w_k<<<5184, 256, 0, stream>>>(Ws, Whi, Wlo);
  transpose_f16_k<<<dim3(32, 24, 32), 256, 0, stream>>>(x, XT);
  // stage-1: hs11 (z=0, W0..3) and hs111 (z=1, W4..7); 128x256 tiles
  gemm_p<<<dim3(128, 6, 2), 512, 131072, stream>>>(Whi, Wlo, XT, bs, hs, 4, 0, 0);
  attn_f_k<<<6144, 256, 0, stream>>>(hs, aoT);
  // final conv: relu(W8 @ attout + b8) -> d_out
  gemm_p<<<dim3(128, 6, 1), 512, 131072, stream>>>(Whi, Wlo, aoT, bs, out, 1, 8, 1);
}

// Round 6
// 622.974 us; speedup vs baseline: 1.5227x; 1.3243x over previous
//
#include <hip/hip_runtime.h>
#include <hip/hip_fp16.h>

typedef unsigned short u16;
typedef float f32x4 __attribute__((ext_vector_type(4)));
typedef _Float16 half8 __attribute__((ext_vector_type(8)));
typedef unsigned short u16x4 __attribute__((ext_vector_type(4)));

#define CDIM 768
#define NP 1024
#define NB 32

static constexpr size_t CHW = (size_t)NB * CDIM * NP;  // 25,165,824

// workspace layout (bytes)
static constexpr size_t XT_OFF  = 0;                         // f16 [b][p][c]; later reused as aoT f16
static constexpr size_t HS_OFF  = CHW * 2;                   // fp32 hs11, hs111 (2*CHW*4)
static constexpr size_t WHI_OFF = HS_OFF + CHW * 8;          // f16 weights

__device__ __forceinline__ u16 f16bits(float f) {
  return __half_as_ushort(__float2half_rn(f));
}

typedef __attribute__((address_space(1))) void gv_t;
typedef __attribute__((address_space(3))) void lv_t;
__device__ __forceinline__ void gload_lds16(const void* g, void* l) {
  __builtin_amdgcn_global_load_lds((gv_t*)g, (lv_t*)l, 16, 0, 0);
}

// ---------------- cast W (fp32 -> f16) ----------------
__global__ __launch_bounds__(256) void cast_w_k(const float* __restrict__ W,
                                                u16* __restrict__ hi) {
  int i = blockIdx.x * 256 + threadIdx.x;
  float4 v = ((const float4*)W)[i];
  u16x4 h4 = {f16bits(v.x), f16bits(v.y), f16bits(v.z), f16bits(v.w)};
  ((u16x4*)hi)[i] = h4;
}

// ---------------- transpose + f16 cast: src fp32 [b][c][p] -> dst f16 [b][p][c] ----------------
__global__ __launch_bounds__(256) void transpose_f16_k(const float* __restrict__ src,
                                                       u16* __restrict__ dxt) {
  __shared__ float tle[32][33];
  const int b = blockIdx.z, c0 = blockIdx.y * 32, p0 = blockIdx.x * 32;
  const int tid = threadIdx.x;
  const int lr = tid >> 5, lc = tid & 31;
  const float* s = src + ((size_t)b * CDIM + c0) * NP + p0;
#pragma unroll
  for (int it = 0; it < 4; ++it) {
    int c = it * 8 + lr;
    tle[c][lc] = s[(size_t)c * NP + lc];
  }
  __syncthreads();
#pragma unroll
  for (int it = 0; it < 4; ++it) {
    int p = it * 8 + lr;
    float v = tle[lc][p];
    size_t off = ((size_t)b * NP + p0 + p) * CDIM + c0 + lc;
    dxt[off] = f16bits(v);
  }
}

// ---------------- spatial permutations ----------------
__device__ __forceinline__ int sigma_fn(int mode, int z, int t, int p) {
  if (t == 0 || mode == 1) return p;
  int i = p >> 5, j = p & 31;
  if (z == 0) {
    if (t == 1) return (j << 5) | (31 - i);
    if (t == 2) return ((31 - i) << 5) | (31 - j);
    return ((31 - j) << 5) | i;
  } else {
    int ib = i & 16, jb = j & 16, il = i & 15, jl = j & 15;
    if (t == 1) return ((ib | jl) << 5) | (jb | (15 - il));
    if (t == 2) return ((ib | (15 - il)) << 5) | (jb | (15 - jl));
    return ((ib | (15 - jl)) << 5) | (jb | il);
  }
}

// ---------------- pipelined multi-term f16 GEMM, BK=64, r4-proven LDS geometry ----------------
// Tile 128(o) x 256(p), 512 threads (8 waves, 2Mx4N, wave tile 64x64), BK=64 channels.
// Per LDS buffer (24576 u16 = 48KB):
//   A [0,8192): [128 rows][8 phys chunks of 8 u16], 128B row stride; phys = logical ^ (row&7)
//   B [8192,24576): 2 k-halves x { [256 rows][4 phys chunks of 8 u16], 64B row stride };
//     phys = logical ^ ((row>>1)&3)
// Depth-1 prefetch, vmcnt(0)+1 barrier per step, steady-state VALU = pointer increments only.
__global__ __launch_bounds__(512, 2) void gemm_p(
    const u16* __restrict__ Whi,
    const u16* __restrict__ Bx,
    const float* __restrict__ bias, float* __restrict__ dst,
    int nterms, int wselBase, int mode) {
  extern __shared__ u16 lds[];  // 2 x 24576 u16
  const int tid = threadIdx.x;
  const int lane = tid & 63;
  const int w = tid >> 6;
  const int wr = w >> 2, wc = w & 3;
  const int z = blockIdx.z;
  const int b = blockIdx.x >> 2;
  const int p0 = (blockIdx.x & 3) << 8;
  const int o0 = blockIdx.y << 7;
  const int l15 = lane & 15, l4 = lane >> 4;
  const int s7 = l15 & 7;

  float* dstz = dst + (size_t)z * CHW;
  const int NSTEP = nterms * 12;

  // LDS read base offsets (u16 units).
  // A frag (m, k-half h): la + baseA_h + m*1024   (m*16 rows x 64 u16/row)
  const int baseA0 = (wr * 64 + l15) * 64 + ((l4) ^ s7) * 8;
  const int baseA1 = (wr * 64 + l15) * 64 + ((4 + l4) ^ s7) * 8;
  // B frag (n, k-half h): la + baseB_h + n*512    (n*16 rows x 32 u16/row)
  const int baseB0 = 8192 + (wc * 64 + l15) * 32 + (l4 ^ ((l15 >> 1) & 3)) * 8;
  const int baseB1 = baseB0 + 8192;

  // staging decode (per-thread constants)
  // A: 1024 slots: d -> row=d>>3, phys=d&7, logical k-chunk = phys^(row&7)
  int arow[2], acof[2];
#pragma unroll
  for (int it = 0; it < 2; ++it) {
    int d = it * 512 + tid;
    arow[it] = d >> 3;
    acof[it] = ((d & 7) ^ (arow[it] & 7)) * 8;
  }
  // B: 2048 slots: d -> half=d>>10, row=(d&1023)>>2, phys=d&3, logical = phys^((row>>1)&3)
  int brow[4], bcof[4];
#pragma unroll
  for (int it = 0; it < 4; ++it) {
    int d = it * 512 + tid;
    int h = d >> 10, rem = d & 1023;
    brow[it] = rem >> 2;
    bcof[it] = h * 32 + (((rem & 3) ^ ((brow[it] >> 1) & 3))) * 8;
  }

  const u16* aptr[2];
  const u16* bptr[4];
  auto setPtrs = [&](int term) {
    int wsel = wselBase + z * 4 + term;
#pragma unroll
    for (int it = 0; it < 2; ++it)
      aptr[it] = Whi + ((size_t)wsel * CDIM + o0 + arow[it]) * CDIM + acof[it];
#pragma unroll
    for (int it = 0; it < 4; ++it) {
      int srow = sigma_fn(mode, z, term, p0 + brow[it]);
      bptr[it] = Bx + ((size_t)b * NP + srow) * CDIM + bcof[it];
    }
  };

  f32x4 acc[4][4], racc[4][4];
#pragma unroll
  for (int m = 0; m < 4; ++m)
#pragma unroll
    for (int n = 0; n < 4; ++n) {
      acc[m][n] = (f32x4){0.f, 0.f, 0.f, 0.f};
      racc[m][n] = (f32x4){0.f, 0.f, 0.f, 0.f};
    }
  float4 bvm[4];

  // prologue: stage step 0 into buf 0
  setPtrs(0);
#pragma unroll
  for (int it = 0; it < 2; ++it) gload_lds16(aptr[it], lds + (it * 512 + tid) * 8);
#pragma unroll
  for (int it = 0; it < 4; ++it) gload_lds16(bptr[it], lds + 8192 + (it * 512 + tid) * 8);
#pragma unroll
  for (int it = 0; it < 2; ++it) aptr[it] += 64;
#pragma unroll
  for (int it = 0; it < 4; ++it) bptr[it] += 64;

  int nsk = 1, nst = 0;        // k-step / term of NEXT stage target
  int ckk = 0, cterm = 0;      // k-step / term being CONSUMED
  int cur = 0;

  for (int s = 0; s < NSTEP; ++s) {
    asm volatile("s_waitcnt vmcnt(0)" ::: "memory");
    __builtin_amdgcn_s_barrier();
    asm volatile("" ::: "memory");

    const u16* la = lds + cur * 24576;
    u16* ldst = lds + (cur ^ 1) * 24576;
    const bool dostage = (s + 1) < NSTEP;

    if (ckk == 0) {
      int wsel = wselBase + z * 4 + cterm;
#pragma unroll
      for (int m = 0; m < 4; ++m)
        bvm[m] = *(const float4*)&bias[wsel * CDIM + o0 + wr * 64 + m * 16 + l4 * 4];
    }
    if (dostage && nsk == 12) { ++nst; nsk = 0; setPtrs(nst); }

    half8 ah[4], bb[4];
    // ======== phase 0 (k-half 0): ds_read; stage A(s+1); 16 MFMA ========
#pragma unroll
    for (int m = 0; m < 4; ++m) ah[m] = *(const half8*)(la + baseA0 + m * 1024);
#pragma unroll
    for (int n = 0; n < 4; ++n) bb[n] = *(const half8*)(la + baseB0 + n * 512);
    if (dostage) {
#pragma unroll
      for (int it = 0; it < 2; ++it) gload_lds16(aptr[it], ldst + (it * 512 + tid) * 8);
    }
    asm volatile("s_waitcnt lgkmcnt(0)" ::: "memory");
    __builtin_amdgcn_s_setprio(1);
#pragma unroll
    for (int m = 0; m < 4; ++m)
#pragma unroll
      for (int n = 0; n < 4; ++n)
        acc[m][n] = __builtin_amdgcn_mfma_f32_16x16x32_f16(ah[m], bb[n], acc[m][n], 0, 0, 0);
    __builtin_amdgcn_s_setprio(0);

    // ======== phase 1 (k-half 1): ds_read; stage B(s+1); 16 MFMA ========
#pragma unroll
    for (int m = 0; m < 4; ++m) ah[m] = *(const half8*)(la + baseA1 + m * 1024);
#pragma unroll
    for (int n = 0; n < 4; ++n) bb[n] = *(const half8*)(la + baseB1 + n * 512);
    if (dostage) {
#pragma unroll
      for (int it = 0; it < 4; ++it) gload_lds16(bptr[it], ldst + 8192 + (it * 512 + tid) * 8);
#pragma unroll
      for (int it = 0; it < 2; ++it) aptr[it] += 64;
#pragma unroll
      for (int it = 0; it < 4; ++it) bptr[it] += 64;
      ++nsk;
    }
    asm volatile("s_waitcnt lgkmcnt(0)" ::: "memory");
    __builtin_amdgcn_s_setprio(1);
#pragma unroll
    for (int m = 0; m < 4; ++m)
#pragma unroll
      for (int n = 0; n < 4; ++n)
        acc[m][n] = __builtin_amdgcn_mfma_f32_16x16x32_f16(ah[m], bb[n], acc[m][n], 0, 0, 0);
    __builtin_amdgcn_s_setprio(0);

    if (ckk == 11) {  // term boundary: relu(acc + bias) -> racc, reset acc
#pragma unroll
      for (int m = 0; m < 4; ++m) {
        float bvf[4] = {bvm[m].x, bvm[m].y, bvm[m].z, bvm[m].w};
#pragma unroll
        for (int n = 0; n < 4; ++n)
#pragma unroll
          for (int r = 0; r < 4; ++r) {
            racc[m][n][r] += fmaxf(0.f, acc[m][n][r] + bvf[r]);
            acc[m][n][r] = 0.f;
          }
      }
    }
    cur ^= 1;
    ++ckk; if (ckk == 12) { ckk = 0; ++cterm; }
  }

  // C write: row = o0+wr*64+m*16+l4*4+r, col = p0+wc*64+n*16+l15
#pragma unroll
  for (int m = 0; m < 4; ++m) {
    int rowb = o0 + wr * 64 + m * 16 + l4 * 4;
#pragma unroll
    for (int n = 0; n < 4; ++n) {
      int col = p0 + wc * 64 + n * 16 + l15;
      float* dp = dstz + ((size_t)b * CDIM + rowb) * NP + col;
#pragma unroll
      for (int r = 0; r < 4; ++r) dp[(size_t)r * NP] = racc[m][n][r];
    }
  }
}

// ---------------- per-(b,c) 32x32 attention, fp32, fused transposed-f16 output ----------------
__global__ __launch_bounds__(256) void attn_f_k(const float* __restrict__ hs, u16* __restrict__ aoT) {
  __shared__ float q[4][1056];   // pitch 33
  __shared__ float kk[4][1056];
  const int tid = threadIdx.x, w = tid >> 6, lane = tid & 63;
  const int pair0 = blockIdx.x * 4;
  const int b = pair0 / CDIM;
  const int c0 = pair0 % CDIM;
#pragma unroll
  for (int it = 0; it < 8; ++it) {
    int d4 = it * 256 + tid;
    int pr = d4 >> 9;
    int mat = (d4 >> 8) & 1;
    int off4 = d4 & 255;
    float4 v = *(const float4*)&hs[(size_t)mat * CHW + (size_t)(pair0 + pr) * NP + off4 * 4];
    float* dl = mat ? kk[pr] : q[pr];
    int off = off4 * 4;
    int base = (off >> 5) * 33 + (off & 31);
    dl[base] = v.x; dl[base + 1] = v.y; dl[base + 2] = v.z; dl[base + 3] = v.w;
  }
  __syncthreads();
  const int i = lane & 31, half = lane >> 5, jb = half * 16;
  const float* Q = q[w];
  const float* K = kk[w];
  float qr[32];
#pragma unroll
  for (int tt = 0; tt < 32; ++tt) qr[tt] = Q[i * 33 + tt];
  float a[16];
#pragma unroll
  for (int j = 0; j < 16; ++j) {
    float s = 0.f;
#pragma unroll
    for (int tt = 0; tt < 32; ++tt) s = fmaf(qr[tt], K[tt * 33 + jb + j], s);
    a[j] = s;
  }
  float mx = a[0];
#pragma unroll
  for (int j = 1; j < 16; ++j) mx = fmaxf(mx, a[j]);
  mx = fmaxf(mx, __shfl_xor(mx, 32));
  float ssum = 0.f;
#pragma unroll
  for (int j = 0; j < 16; ++j) { a[j] = expf(a[j] - mx); ssum += a[j]; }
  ssum += __shfl_xor(ssum, 32);
  float inv = 1.f / ssum;
#pragma unroll
  for (int j = 0; j < 16; ++j) a[j] *= inv;
#pragma unroll
  for (int h = 0; h < 32; ++h) {
    float o = 0.f;
#pragma unroll
    for (int j = 0; j < 16; ++j) o = fmaf(a[j], Q[(jb + j) * 33 + h], o);
    o += __shfl_xor(o, 32);
    if (half == (h >> 4)) kk[w][i * 33 + h] = o;
  }
  __syncthreads();
#pragma unroll
  for (int it = 0; it < 4; ++it) {
    int p = it * 256 + tid;
    int base = (p >> 5) * 33 + (p & 31);
    ushort4 v;
    v.x = f16bits(kk[0][base]);
    v.y = f16bits(kk[1][base]);
    v.z = f16bits(kk[2][base]);
    v.w = f16bits(kk[3][base]);
    *(ushort4*)&aoT[((size_t)b * NP + p) * CDIM + c0] = v;
  }
}

extern "C" void kernel_launch(void* const* d_in, const int* in_sizes, int n_in,
                              void* d_out, int out_size, void* d_ws, size_t ws_size,
                              hipStream_t stream) {
  (void)in_sizes; (void)n_in; (void)out_size; (void)ws_size;
  const float* x = (const float*)d_in[0];
  const float* Ws = (const float*)d_in[1];
  const float* bs = (const float*)d_in[2];
  float* out = (float*)d_out;
  char* ws = (char*)d_ws;

  u16* XT  = (u16*)(ws + XT_OFF);
  float* hs = (float*)(ws + HS_OFF);
  u16* Whi = (u16*)(ws + WHI_OFF);
  u16* aoT = (u16*)(ws + XT_OFF);   // aliases XT (dead after stage-1)

  cast_w_k<<<5184, 256, 0, stream>>>(Ws, Whi);
  transpose_f16_k<<<dim3(32, 24, 32), 256, 0, stream>>>(x, XT);
  // stage-1: hs11 (z=0, W0..3) and hs111 (z=1, W4..7); 128x256 tiles
  gemm_p<<<dim3(128, 6, 2), 512, 98304, stream>>>(Whi, XT, bs, hs, 4, 0, 0);
  attn_f_k<<<6144, 256, 0, stream>>>(hs, aoT);
  // final conv: relu(W8 @ attout + b8) -> d_out
  gemm_p<<<dim3(128, 6, 1), 512, 98304, stream>>>(Whi, aoT, bs, out, 1, 8, 1);
}